// Round 3
// baseline (129.076 us; speedup 1.0000x reference)
//
#include <hip/hip_runtime.h>
#include <math.h>

// Dims fixed by reference setup_inputs
#define B_ 4
#define S_ 2048
#define D_ 1024
#define G_ 512
#define T_ 2047          // diff rows per batch
#define R_ 8188          // B_*T_ valid rows
#define RPAD 8192
#define MT 32            // diff rows per fused block (grid 256 = 1 block/CU)
#define ABST 520         // AB LDS row stride (elems): 1040 B, 16-B aligned, 2-way bank alias

typedef __attribute__((ext_vector_type(8))) short short8;
typedef __attribute__((ext_vector_type(4))) short s16x4;
typedef __attribute__((ext_vector_type(4))) float f32x4;
typedef __attribute__((ext_vector_type(4))) unsigned short u16x4;

// ws byte offsets
#define WSOFF_RG2  0u           // 512 f
#define WSOFF_MAGW 2048u        // 8192 f
#define WSOFF_RMAG 34816u       // 8192 f
#define WSOFF_BP1  67584u       // Bpack1 [128][512] short8 (1 MB)
#define WSOFF_BP2  1116160u     // Bpack2 [64][1024] short8 (1 MB)
#define WSOFF_NH   2164736u     // normh (RAW diffs) [8192][1024] bf16 (16 MB)
#define WSOFF_IH   18941952u    // inflh [8192][1024] bf16 (16 MB)

__device__ inline short to_bf16(float f) {
    union { float f; unsigned u; } v; v.f = f;
    unsigned r = v.u + 0x7fffu + ((v.u >> 16) & 1u);
    return (short)(r >> 16);
}
__device__ inline float fb(unsigned short h) {
    union { unsigned u; float f; } v;
    v.u = ((unsigned)h) << 16;
    return v.f;
}
__device__ inline f32x4 MF(short8 a, short8 b, f32x4 c) {
    return __builtin_amdgcn_mfma_f32_16x16x32_bf16(a, b, c, 0, 0, 0);
}

// raw barrier: LDS-visibility only, does NOT drain vmcnt (keeps global
// loads/stores in flight across phases)
#define RAWBAR() do {                                            \
    __builtin_amdgcn_sched_barrier(0);                           \
    asm volatile("s_waitcnt lgkmcnt(0)" ::: "memory");           \
    __builtin_amdgcn_s_barrier();                                \
    __builtin_amdgcn_sched_barrier(0);                           \
} while (0)

// ---------------------------------------------------------------------------
// prep (merged):
//  bid<128 : per-wave g = bid*4+wave: rg2[g] = 2/max(||guid[g]||,1e-8);
//            Bpack1[k/8][g][k&7] = bf16(guid[g][k])
//  bid>=128: gg = bid-128: Bpack2[gg][d][j] = bf16(guid[gg*8+j][d])
// ---------------------------------------------------------------------------
__global__ __launch_bounds__(256) void prep_kernel(const float* __restrict__ guid,
                                                   float* __restrict__ rg2,
                                                   short8* __restrict__ Bp1,
                                                   short8* __restrict__ Bp2) {
    int bid = blockIdx.x, tid = threadIdx.x;
    if (bid < 128) {
        int wave = tid >> 6, lane = tid & 63;
        int g = bid * 4 + wave;
        const float4* gp = (const float4*)(guid + (size_t)g * D_);
        float ss = 0.f;
#pragma unroll
        for (int i = 0; i < 4; ++i) {
            float4 v = gp[lane + 64 * i];
            ss += v.x * v.x + v.y * v.y + v.z * v.z + v.w * v.w;
        }
#pragma unroll
        for (int m = 32; m >= 1; m >>= 1) ss += __shfl_xor(ss, m, 64);
        if (lane == 0) rg2[g] = 2.0f / fmaxf(sqrtf(ss), 1e-8f);
#pragma unroll
        for (int h = 0; h < 2; ++h) {
            int kg = lane + 64 * h;
            const float* src = guid + (size_t)g * D_ + kg * 8;
            short8 v;
#pragma unroll
            for (int j = 0; j < 8; ++j) v[j] = to_bf16(src[j]);
            Bp1[(size_t)kg * G_ + g] = v;
        }
    } else {
        int gg = bid - 128;
#pragma unroll
        for (int dd = 0; dd < 4; ++dd) {
            int d = tid + 256 * dd;
            short8 v;
#pragma unroll
            for (int j = 0; j < 8; ++j) v[j] = to_bf16(guid[(size_t)(gg * 8 + j) * D_ + d]);
            Bp2[(size_t)gg * D_ + d] = v;
        }
    }
}

// one 16x16x32 step of gemm1 for k-group ksv using B-ring entry q
#define G1Q(ksv, q)  {                                                        \
    short8 a0 = *(const short8*)&AB[l15][(ksv) * 32 + quad * 8];              \
    short8 a1 = *(const short8*)&AB[16 + l15][(ksv) * 32 + quad * 8];         \
    acc1[0][0] = MF(a0, q[0], acc1[0][0]); acc1[0][1] = MF(a0, q[1], acc1[0][1]); \
    acc1[1][0] = MF(a1, q[0], acc1[1][0]); acc1[1][1] = MF(a1, q[1], acc1[1][1]); }

// ---------------------------------------------------------------------------
// fused: 32-row tile, 16 waves, grid 256 (1 block/CU).
// Raw bf16 diffs (deferred normalization); 4-deep B prefetch in gemm1,
// 2-deep in gemm2; softmax without max-subtraction (logits bounded in
// [-2,2]); 1/sum folded into gemm2 epilogue; raw (non-vmcnt) barriers.
// ---------------------------------------------------------------------------
__global__ __launch_bounds__(1024, 4) void fused_kernel(const float* __restrict__ emb,
                                                        const short8* __restrict__ Bp1,
                                                        const short8* __restrict__ Bp2,
                                                        const float* __restrict__ rg2,
                                                        float* __restrict__ magw,
                                                        float* __restrict__ rmagA,
                                                        short* __restrict__ normh,
                                                        short* __restrict__ inflh) {
    __shared__ short AB[MT][ABST];      // raw diff halves, then exp-weights
    __shared__ float rg2s[G_];
    __shared__ float pred[MT][16];
    __shared__ float redrs[MT];
    __shared__ float rmagS[MT];

    const int tid = threadIdx.x;
    const int wave = tid >> 6, lane = tid & 63;
    const int l15 = lane & 15, quad = lane >> 4;
    const int r0 = blockIdx.x * MT;

    if (tid < G_) rg2s[tid] = rg2[tid];

    // ---- Phase 1a: rows 2w,2w+1: k<512 diff -> raw bf16 LDS + normh ----
    const float4* prow[2];
    float ssp[2];
    int Rrow[2];
#pragma unroll
    for (int i = 0; i < 2; ++i) {
        int rr = wave * 2 + i;
        int R = r0 + rr;
        Rrow[i] = R;
        float ss = 0.f;
        if (R < R_) {
            int b = R / T_;
            int t = R - b * T_;
            const float4* p = (const float4*)(emb + ((size_t)b * S_ + t) * D_);
            prow[i] = p;
            short* nb = normh + (size_t)R * D_ + 4 * lane;
#pragma unroll
            for (int j = 0; j < 2; ++j) {
                float4 x0 = p[lane + 64 * j];
                float4 x1 = p[lane + 64 * j + 256];
                float4 dv = make_float4(x1.x - x0.x, x1.y - x0.y, x1.z - x0.z, x1.w - x0.w);
                ss += dv.x * dv.x + dv.y * dv.y + dv.z * dv.z + dv.w * dv.w;
                s16x4 h;
                h[0] = to_bf16(dv.x); h[1] = to_bf16(dv.y);
                h[2] = to_bf16(dv.z); h[3] = to_bf16(dv.w);
                *(s16x4*)(nb + 256 * j) = h;
                *(s16x4*)&AB[rr][4 * lane + 256 * j] = h;
            }
        } else {
            prow[i] = (const float4*)emb;   // dummy, never consumed
            s16x4 z = (s16x4)0;
            *(s16x4*)&AB[rr][4 * lane] = z;
            *(s16x4*)&AB[rr][4 * lane + 256] = z;
        }
        ssp[i] = ss;
    }
    RAWBAR();                    // LDS visible; no vmcnt drain

    // ---- Phase 2a: gemm1 pass 0 (k < 512), 4-deep B ring ----
    f32x4 acc1[2][2];
#pragma unroll
    for (int mt = 0; mt < 2; ++mt)
#pragma unroll
        for (int nt = 0; nt < 2; ++nt) acc1[mt][nt] = (f32x4)0.f;

    float4 hx0[2][2], hx1[2][2];
    {
        const short8* Bb = Bp1 + (size_t)quad * G_ + wave * 32 + l15;
        short8 q0[2], q1[2], q2[2], q3[2];
        q0[0] = Bb[0];          q0[1] = Bb[16];
        q1[0] = Bb[4 * G_];     q1[1] = Bb[4 * G_ + 16];
        q2[0] = Bb[8 * G_];     q2[1] = Bb[8 * G_ + 16];
        q3[0] = Bb[12 * G_];    q3[1] = Bb[12 * G_ + 16];
        // issue k>=512 emb loads AFTER the ring preload: the ring's vmcnt
        // waits then never have to drain these HBM loads
#pragma unroll
        for (int i = 0; i < 2; ++i) {
            if (Rrow[i] < R_) {
#pragma unroll
                for (int j = 0; j < 2; ++j) {
                    hx0[i][j] = prow[i][lane + 64 * (j + 2)];
                    hx1[i][j] = prow[i][lane + 64 * (j + 2) + 256];
                }
            } else {
                hx0[i][0] = make_float4(0.f, 0.f, 0.f, 0.f);
                hx0[i][1] = make_float4(0.f, 0.f, 0.f, 0.f);
                hx1[i][0] = make_float4(0.f, 0.f, 0.f, 0.f);
                hx1[i][1] = make_float4(0.f, 0.f, 0.f, 0.f);
            }
        }
#pragma unroll
        for (int k4 = 0; k4 < 16; k4 += 4) {
            G1Q(k4 + 0, q0); if (k4 < 12) { q0[0] = Bb[(k4 + 4) * 4 * G_]; q0[1] = Bb[(k4 + 4) * 4 * G_ + 16]; }
            G1Q(k4 + 1, q1); if (k4 < 12) { q1[0] = Bb[(k4 + 5) * 4 * G_]; q1[1] = Bb[(k4 + 5) * 4 * G_ + 16]; }
            G1Q(k4 + 2, q2); if (k4 < 12) { q2[0] = Bb[(k4 + 6) * 4 * G_]; q2[1] = Bb[(k4 + 6) * 4 * G_ + 16]; }
            G1Q(k4 + 3, q3); if (k4 < 12) { q3[0] = Bb[(k4 + 7) * 4 * G_]; q3[1] = Bb[(k4 + 7) * 4 * G_ + 16]; }
        }
    }

    // ---- Phase 1b: finish k>=512 halves, full-row norm, rmag ----
    s16x4 holdh[2][2];
#pragma unroll
    for (int i = 0; i < 2; ++i) {
        int R = Rrow[i];
        int rr = wave * 2 + i;
        float ss = ssp[i];
        if (R < R_) {
            short* nb = normh + (size_t)R * D_ + 4 * lane;
#pragma unroll
            for (int j = 0; j < 2; ++j) {
                float4 dv = make_float4(hx1[i][j].x - hx0[i][j].x, hx1[i][j].y - hx0[i][j].y,
                                        hx1[i][j].z - hx0[i][j].z, hx1[i][j].w - hx0[i][j].w);
                ss += dv.x * dv.x + dv.y * dv.y + dv.z * dv.z + dv.w * dv.w;
                s16x4 h;
                h[0] = to_bf16(dv.x); h[1] = to_bf16(dv.y);
                h[2] = to_bf16(dv.z); h[3] = to_bf16(dv.w);
                *(s16x4*)(nb + 256 * (j + 2)) = h;
                holdh[i][j] = h;
            }
        } else {
            holdh[i][0] = (s16x4)0; holdh[i][1] = (s16x4)0;
        }
#pragma unroll
        for (int m = 32; m >= 1; m >>= 1) ss += __shfl_xor(ss, m, 64);
        float mag = sqrtf(ss);
        float rmag = (mag > 1e-6f) ? (1.0f / mag) : 0.0f;
        if (lane == 0) {
            rmagS[rr] = rmag;
            if (R < R_) { magw[R] = tanhf(2.0f * mag); rmagA[R] = rmag; }
        }
    }
    RAWBAR();                    // all pass-0 LDS reads done
#pragma unroll
    for (int i = 0; i < 2; ++i) {
        int rr = wave * 2 + i;
        *(s16x4*)&AB[rr][4 * lane] = holdh[i][0];
        *(s16x4*)&AB[rr][4 * lane + 256] = holdh[i][1];
    }
    RAWBAR();

    // ---- Phase 2b: gemm1 pass 1 (k >= 512), 4-deep B ring ----
    {
        const short8* Bb = Bp1 + (size_t)(64 + quad) * G_ + wave * 32 + l15;
        short8 q0[2], q1[2], q2[2], q3[2];
        q0[0] = Bb[0];          q0[1] = Bb[16];
        q1[0] = Bb[4 * G_];     q1[1] = Bb[4 * G_ + 16];
        q2[0] = Bb[8 * G_];     q2[1] = Bb[8 * G_ + 16];
        q3[0] = Bb[12 * G_];    q3[1] = Bb[12 * G_ + 16];
#pragma unroll
        for (int k4 = 0; k4 < 16; k4 += 4) {
            G1Q(k4 + 0, q0); if (k4 < 12) { q0[0] = Bb[(k4 + 4) * 4 * G_]; q0[1] = Bb[(k4 + 4) * 4 * G_ + 16]; }
            G1Q(k4 + 1, q1); if (k4 < 12) { q1[0] = Bb[(k4 + 5) * 4 * G_]; q1[1] = Bb[(k4 + 5) * 4 * G_ + 16]; }
            G1Q(k4 + 2, q2); if (k4 < 12) { q2[0] = Bb[(k4 + 6) * 4 * G_]; q2[1] = Bb[(k4 + 6) * 4 * G_ + 16]; }
            G1Q(k4 + 3, q3); if (k4 < 12) { q3[0] = Bb[(k4 + 7) * 4 * G_]; q3[1] = Bb[(k4 + 7) * 4 * G_ + 16]; }
        }
    }

    // ---- gemm2 first-B prefetch: in flight across the softmax ----
    const short8* Bb2 = Bp2 + (size_t)quad * D_ + wave * 64 + l15;
    short8 c0[4];
#pragma unroll
    for (int nt = 0; nt < 4; ++nt) c0[nt] = Bb2[nt * 16];

    // ---- Phase 3: softmax WITHOUT max-subtraction (logits in [-2,2]).
    //      Unnormalized exp -> AB; 1/sum deferred to gemm2 epilogue. ----
    {
        float rmv[2][4];
#pragma unroll
        for (int mt = 0; mt < 2; ++mt)
#pragma unroll
            for (int r2 = 0; r2 < 4; ++r2) rmv[mt][r2] = rmagS[mt * 16 + quad * 4 + r2];
        float psum[2][4];
#pragma unroll
        for (int mt = 0; mt < 2; ++mt)
#pragma unroll
            for (int r2 = 0; r2 < 4; ++r2) psum[mt][r2] = 0.f;
#pragma unroll
        for (int mt = 0; mt < 2; ++mt)
#pragma unroll
            for (int nt = 0; nt < 2; ++nt) {
                float rgv = rg2s[wave * 32 + nt * 16 + l15];
#pragma unroll
                for (int r2 = 0; r2 < 4; ++r2) {
                    float e = __expf(acc1[mt][nt][r2] * rgv * rmv[mt][r2]);
                    acc1[mt][nt][r2] = e;
                    psum[mt][r2] += e;
                }
            }
#pragma unroll
        for (int m = 8; m >= 1; m >>= 1)
#pragma unroll
            for (int mt = 0; mt < 2; ++mt)
#pragma unroll
                for (int r2 = 0; r2 < 4; ++r2)
                    psum[mt][r2] += __shfl_xor(psum[mt][r2], m, 16);
        RAWBAR();                // all pass-1 LDS reads done -> safe to overwrite AB
#pragma unroll
        for (int mt = 0; mt < 2; ++mt)
#pragma unroll
            for (int nt = 0; nt < 2; ++nt)
#pragma unroll
                for (int r2 = 0; r2 < 4; ++r2)
                    AB[mt * 16 + quad * 4 + r2][wave * 32 + nt * 16 + l15] =
                        to_bf16(acc1[mt][nt][r2]);
        if (l15 == 0) {
#pragma unroll
            for (int mt = 0; mt < 2; ++mt)
#pragma unroll
                for (int r2 = 0; r2 < 4; ++r2)
                    pred[mt * 16 + quad * 4 + r2][wave] = psum[mt][r2];
        }
    }
    RAWBAR();
    if (tid < MT) {              // wave 0 computes 1/sum while others start gemm2
        float s = 0.f;
#pragma unroll
        for (int w2 = 0; w2 < 16; ++w2) s += pred[tid][w2];
        redrs[tid] = 1.0f / s;
    }

    // ---- Phase 4: gemm2, 2-deep B ring. wave owns d in [64w, 64w+64) ----
    f32x4 acc2[2][4];
#pragma unroll
    for (int mt = 0; mt < 2; ++mt)
#pragma unroll
        for (int nt = 0; nt < 4; ++nt) acc2[mt][nt] = (f32x4)0.f;
    {
        short8 c1[4];
#pragma unroll
        for (int nt = 0; nt < 4; ++nt) c1[nt] = Bb2[4 * D_ + nt * 16];
#pragma unroll
        for (int k2 = 0; k2 < 16; k2 += 2) {
            {
                short8 a0 = *(const short8*)&AB[l15][k2 * 32 + quad * 8];
                short8 a1 = *(const short8*)&AB[16 + l15][k2 * 32 + quad * 8];
#pragma unroll
                for (int nt = 0; nt < 4; ++nt) {
                    acc2[0][nt] = MF(a0, c0[nt], acc2[0][nt]);
                    acc2[1][nt] = MF(a1, c0[nt], acc2[1][nt]);
                }
                if (k2 < 14) {
#pragma unroll
                    for (int nt = 0; nt < 4; ++nt) c0[nt] = Bb2[(k2 + 2) * 4 * D_ + nt * 16];
                }
            }
            {
                short8 a0 = *(const short8*)&AB[l15][(k2 + 1) * 32 + quad * 8];
                short8 a1 = *(const short8*)&AB[16 + l15][(k2 + 1) * 32 + quad * 8];
#pragma unroll
                for (int nt = 0; nt < 4; ++nt) {
                    acc2[0][nt] = MF(a0, c1[nt], acc2[0][nt]);
                    acc2[1][nt] = MF(a1, c1[nt], acc2[1][nt]);
                }
                if (k2 < 14) {
#pragma unroll
                    for (int nt = 0; nt < 4; ++nt) c1[nt] = Bb2[(k2 + 3) * 4 * D_ + nt * 16];
                }
            }
        }
    }
    RAWBAR();                    // redrs (written by wave 0) now visible

    // ---- Phase 5: influence bf16 out, scaled by 1/sum ----
#pragma unroll
    for (int mt = 0; mt < 2; ++mt)
#pragma unroll
        for (int nt = 0; nt < 4; ++nt) {
            int d = wave * 64 + nt * 16 + l15;
#pragma unroll
            for (int r2 = 0; r2 < 4; ++r2) {
                int row = mt * 16 + quad * 4 + r2;
                int R = r0 + row;
                if (R < R_) inflh[(size_t)R * D_ + d] = to_bf16(acc2[mt][nt][r2] * redrs[row]);
            }
        }
}

// ---------------------------------------------------------------------------
// combine: 8-tap ring over RAW bf16 normh (scaled by rmag at load) + inflh.
// block = 8 s x 1024 d, 256 threads, 4 d/thread. grid 1024 -> 16 waves/CU.
// 2-deep double-buffered row prefetch, fully unrolled.
// ---------------------------------------------------------------------------
__global__ __launch_bounds__(256) void combine_kernel(const float* __restrict__ magw,
                                                      const float* __restrict__ rmagA,
                                                      const unsigned short* __restrict__ normh,
                                                      const unsigned short* __restrict__ inflh,
                                                      float* __restrict__ out) {
    int blk = blockIdx.x;
    int b = blk >> 8;
    int s0 = (blk & 255) * 8;      // multiple of 8 -> slot arithmetic static
    int d0 = threadIdx.x * 4;
    size_t rbase = (size_t)b * T_;
    float* ob = out + ((size_t)b * S_ + s0) * D_ + d0;

    f32x4 ring[8]; float mring[8];
#pragma unroll
    for (int j = 0; j < 8; ++j) { ring[j] = (f32x4)0.f; mring[j] = 0.f; }

#define CLOAD(t_, N_, I_, M_, RV_) {                                     \
        size_t off_ = (rbase + (t_)) * D_ + d0;                          \
        N_ = *(const u16x4*)(normh + off_);                              \
        I_ = *(const u16x4*)(inflh + off_);                              \
        M_ = magw[rbase + (t_)];                                         \
        RV_ = rmagA[rbase + (t_)]; }

#define CBLEND(slot_, N_, I_, M_, RV_) {                                 \
        float ns_ = 0.6f * (RV_);                                        \
        ring[slot_][0] = ns_ * fb(N_[0]) + 0.4f * fb(I_[0]);             \
        ring[slot_][1] = ns_ * fb(N_[1]) + 0.4f * fb(I_[1]);             \
        ring[slot_][2] = ns_ * fb(N_[2]) + 0.4f * fb(I_[2]);             \
        ring[slot_][3] = ns_ * fb(N_[3]) + 0.4f * fb(I_[3]);             \
        mring[slot_] = (M_); }

#define CTAPS(i_) {                                                      \
        f32x4 acc = (f32x4)0.f; float wsum = 0.f;                        \
        _Pragma("unroll")                                                \
        for (int a = 1; a <= 8; ++a) {                                   \
            int slot = ((i_) - a) & 7;                                   \
            float lin = 0.1f + (0.9f / 7.0f) * (float)(8 - a);           \
            float wt = lin * mring[slot];                                \
            acc[0] += wt * ring[slot][0]; acc[1] += wt * ring[slot][1];  \
            acc[2] += wt * ring[slot][2]; acc[3] += wt * ring[slot][3];  \
            wsum += wt; }                                                \
        float rws = 1.0f / fmaxf(wsum, 1e-8f);                           \
        f32x4 o; o[0] = acc[0] * rws; o[1] = acc[1] * rws;               \
        o[2] = acc[2] * rws; o[3] = acc[3] * rws;                        \
        *(f32x4*)(ob + (size_t)(i_) * D_) = o; }

    if (s0 != 0) {
#pragma unroll
        for (int j = 0; j < 8; ++j) {
            int t = s0 - 8 + j;
            u16x4 n4, i4; float pm, pr;
            CLOAD(t, n4, i4, pm, pr);
            CBLEND(j, n4, i4, pm, pr);
        }
        u16x4 An, Ai, Bn, Bi; float Am, Ar, Bm, Br;
        CLOAD(s0,     An, Ai, Am, Ar);
        CLOAD(s0 + 1, Bn, Bi, Bm, Br);
        CTAPS(0); CBLEND(0, An, Ai, Am, Ar); CLOAD(s0 + 2, An, Ai, Am, Ar);
        CTAPS(1); CBLEND(1, Bn, Bi, Bm, Br); CLOAD(s0 + 3, Bn, Bi, Bm, Br);
        CTAPS(2); CBLEND(2, An, Ai, Am, Ar); CLOAD(s0 + 4, An, Ai, Am, Ar);
        CTAPS(3); CBLEND(3, Bn, Bi, Bm, Br); CLOAD(s0 + 5, Bn, Bi, Bm, Br);
        CTAPS(4); CBLEND(4, An, Ai, Am, Ar); CLOAD(s0 + 6, An, Ai, Am, Ar);
        CTAPS(5); CBLEND(5, Bn, Bi, Bm, Br);
        CTAPS(6); CBLEND(6, An, Ai, Am, Ar);
        CTAPS(7);
    } else {
        // first tile: growing window, 4 blocks total -> simple path
#pragma unroll
        for (int i = 0; i < 8; ++i) {
            if (i >= 1) {
                int t = i - 1;
                u16x4 n4, i4; float pm, pr;
                CLOAD(t, n4, i4, pm, pr);
                CBLEND((i - 1) & 7, n4, i4, pm, pr);
            }
            const int w = i;
            f32x4 acc = (f32x4)0.f; float wsum = 0.f;
            if (w > 0) {
                const float rw = (w > 1) ? 0.9f / (float)(w - 1) : 0.0f;
#pragma unroll
                for (int a = 1; a <= 8; ++a) {
                    if (a <= w) {
                        int slot = (i - a) & 7;
                        float lin = 0.1f + rw * (float)(w - a);
                        float wt = lin * mring[slot];
                        acc[0] += wt * ring[slot][0]; acc[1] += wt * ring[slot][1];
                        acc[2] += wt * ring[slot][2]; acc[3] += wt * ring[slot][3];
                        wsum += wt;
                    }
                }
            }
            float rws = 1.0f / fmaxf(wsum, 1e-8f);
            f32x4 o; o[0] = acc[0] * rws; o[1] = acc[1] * rws;
            o[2] = acc[2] * rws; o[3] = acc[3] * rws;
            *(f32x4*)(ob + (size_t)i * D_) = o;
        }
    }
#undef CLOAD
#undef CBLEND
#undef CTAPS
}

// ---------------------------------------------------------------------------
extern "C" void kernel_launch(void* const* d_in, const int* in_sizes, int n_in,
                              void* d_out, int out_size, void* d_ws, size_t ws_size,
                              hipStream_t stream) {
    const float* emb  = (const float*)d_in[0];
    const float* guid = (const float*)d_in[1];
    float* out = (float*)d_out;
    char* ws = (char*)d_ws;

    float*  rg2   = (float*)(ws + WSOFF_RG2);
    float*  magw  = (float*)(ws + WSOFF_MAGW);
    float*  rmagA = (float*)(ws + WSOFF_RMAG);
    short8* Bp1   = (short8*)(ws + WSOFF_BP1);
    short8* Bp2   = (short8*)(ws + WSOFF_BP2);
    short*  normh = (short*)(ws + WSOFF_NH);
    short*  inflh = (short*)(ws + WSOFF_IH);

    prep_kernel<<<192, 256, 0, stream>>>(guid, rg2, Bp1, Bp2);
    fused_kernel<<<RPAD / MT, 1024, 0, stream>>>(emb, Bp1, Bp2, rg2, magw, rmagA, normh, inflh);
    combine_kernel<<<B_ * 256, 256, 0, stream>>>(magw, rmagA, (const unsigned short*)normh,
                                                 (const unsigned short*)inflh, out);
}

// Round 4
// 121.071 us; speedup vs baseline: 1.0661x; 1.0661x over previous
//
#include <hip/hip_runtime.h>
#include <math.h>

// Dims fixed by reference setup_inputs
#define B_ 4
#define S_ 2048
#define D_ 1024
#define G_ 512
#define T_ 2047          // diff rows per batch
#define MTO 32           // output rows per block (grid 256 = 1 block/CU)
#define NR 48            // padded pipeline rows (39 used: 32 outputs + 8-row halo)
#define ABST2 1032       // ABs stride (elems): 2064 B, 16-B aligned
#define VST 520          // Vs stride

typedef __attribute__((ext_vector_type(8))) short short8;
typedef __attribute__((ext_vector_type(4))) short s16x4;
typedef __attribute__((ext_vector_type(4))) float f32x4;

// ws byte offsets
#define WSOFF_RG2 0u                 // 512 f
#define WSOFF_BP1 4096u              // Bpack1 [128][512] short8 (1 MB)
#define WSOFF_BP2 (4096u + 1048576u) // Bpack2 [64][1024] short8 (1 MB)

__device__ inline short to_bf16(float f) {
    union { float f; unsigned u; } v; v.f = f;
    unsigned r = v.u + 0x7fffu + ((v.u >> 16) & 1u);
    return (short)(r >> 16);
}
__device__ inline float fb(unsigned short h) {
    union { unsigned u; float f; } v;
    v.u = ((unsigned)h) << 16;
    return v.f;
}
__device__ inline float fbs(short h) { return fb((unsigned short)h); }
__device__ inline f32x4 MF(short8 a, short8 b, f32x4 c) {
    return __builtin_amdgcn_mfma_f32_16x16x32_bf16(a, b, c, 0, 0, 0);
}

// raw barrier: LDS-visibility only, does NOT drain vmcnt
#define RAWBAR() do {                                            \
    __builtin_amdgcn_sched_barrier(0);                           \
    asm volatile("s_waitcnt lgkmcnt(0)" ::: "memory");           \
    __builtin_amdgcn_s_barrier();                                \
    __builtin_amdgcn_sched_barrier(0);                           \
} while (0)

// ---------------------------------------------------------------------------
// prep (merged):
//  bid<128 : per-wave g = bid*4+wave: rg2[g] = 2/max(||guid[g]||,1e-8);
//            Bpack1[k/8][g][k&7] = bf16(guid[g][k])
//  bid>=128: gg = bid-128: Bpack2[gg][d][j] = bf16(guid[gg*8+j][d])
// ---------------------------------------------------------------------------
__global__ __launch_bounds__(256) void prep_kernel(const float* __restrict__ guid,
                                                   float* __restrict__ rg2,
                                                   short8* __restrict__ Bp1,
                                                   short8* __restrict__ Bp2) {
    int bid = blockIdx.x, tid = threadIdx.x;
    if (bid < 128) {
        int wave = tid >> 6, lane = tid & 63;
        int g = bid * 4 + wave;
        const float4* gp = (const float4*)(guid + (size_t)g * D_);
        float ss = 0.f;
#pragma unroll
        for (int i = 0; i < 4; ++i) {
            float4 v = gp[lane + 64 * i];
            ss += v.x * v.x + v.y * v.y + v.z * v.z + v.w * v.w;
        }
#pragma unroll
        for (int m = 32; m >= 1; m >>= 1) ss += __shfl_xor(ss, m, 64);
        if (lane == 0) rg2[g] = 2.0f / fmaxf(sqrtf(ss), 1e-8f);
#pragma unroll
        for (int h = 0; h < 2; ++h) {
            int kg = lane + 64 * h;
            const float* src = guid + (size_t)g * D_ + kg * 8;
            short8 v;
#pragma unroll
            for (int j = 0; j < 8; ++j) v[j] = to_bf16(src[j]);
            Bp1[(size_t)kg * G_ + g] = v;
        }
    } else {
        int gg = bid - 128;
#pragma unroll
        for (int dd = 0; dd < 4; ++dd) {
            int d = tid + 256 * dd;
            short8 v;
#pragma unroll
            for (int j = 0; j < 8; ++j) v[j] = to_bf16(guid[(size_t)(gg * 8 + j) * D_ + d]);
            Bp2[(size_t)gg * D_ + d] = v;
        }
    }
}

// one gemm1 K-step for k-group ksv using B-ring entry q (3 m-tiles)
#define G1Q3(ksv, q)  {                                                           \
    short8 a0 = *(const short8*)&ABs[l15][(ksv) * 32 + quad * 8];                 \
    short8 a1 = *(const short8*)&ABs[16 + l15][(ksv) * 32 + quad * 8];            \
    short8 a2 = *(const short8*)&ABs[32 + l15][(ksv) * 32 + quad * 8];            \
    acc1[0][0] = MF(a0, q[0], acc1[0][0]); acc1[0][1] = MF(a0, q[1], acc1[0][1]); \
    acc1[1][0] = MF(a1, q[0], acc1[1][0]); acc1[1][1] = MF(a1, q[1], acc1[1][1]); \
    acc1[2][0] = MF(a2, q[0], acc1[2][0]); acc1[2][1] = MF(a2, q[1], acc1[2][1]); }

// ---------------------------------------------------------------------------
// fused_kernel: everything. Block = (b, s0): 32 output rows. Computes 39 diff
// rows (halo recompute), gemm1 [48x512], softmax, tap-combined weights V
// [32x512], gemm2 V*guid = influence part of OUTPUT, plus in-LDS 8-tap FIR
// over raw diffs for the normed part. Writes final f32 out. No combine kernel,
// no normh/inflh round-trip.
// ---------------------------------------------------------------------------
__global__ __launch_bounds__(1024, 4) void fused_kernel(const float* __restrict__ emb,
                                                        const short8* __restrict__ Bp1,
                                                        const short8* __restrict__ Bp2,
                                                        const float* __restrict__ rg2,
                                                        float* __restrict__ out) {
    __shared__ short ABs[NR][ABST2];     // raw diffs full-K; then W (cols<512); then IP [32][ABST2]
    __shared__ short Vs[MTO][VST];       // tap-combined weights (gemm2 A)
    __shared__ float rg2s[G_];
    __shared__ float pred[NR][16];
    __shared__ float magS[NR], rmagS[NR], mrS[NR], cvS[NR];
    __shared__ float rwsS[MTO];

    const int tid = threadIdx.x;
    const int wave = tid >> 6, lane = tid & 63;
    const int l15 = lane & 15, quad = lane >> 4;
    const int bid = blockIdx.x;
    const int b = bid >> 6;
    const int s0 = (bid & 63) << 5;
    const bool edge = (s0 == 0);

    if (tid < G_) rg2s[tid] = rg2[tid];

    // ---- Phase 1: diffs. wave handles rows {w, 16+w, 32+w}; row rr -> t = s0-8+rr ----
#pragma unroll
    for (int ii = 0; ii < 3; ++ii) {
        int rr = wave + 16 * ii;
        int t = s0 - 8 + rr;
        bool valid = (t >= 0) && (rr < 39);
        float ss = 0.f;
        if (valid) {
            const float4* p = (const float4*)(emb + ((size_t)b * S_ + t) * D_);
#pragma unroll
            for (int j = 0; j < 4; ++j) {
                float4 x0 = p[lane + 64 * j];
                float4 x1 = p[lane + 64 * j + 256];
                float4 dv = make_float4(x1.x - x0.x, x1.y - x0.y, x1.z - x0.z, x1.w - x0.w);
                ss += dv.x * dv.x + dv.y * dv.y + dv.z * dv.z + dv.w * dv.w;
                s16x4 h;
                h[0] = to_bf16(dv.x); h[1] = to_bf16(dv.y);
                h[2] = to_bf16(dv.z); h[3] = to_bf16(dv.w);
                *(s16x4*)&ABs[rr][4 * lane + 256 * j] = h;
            }
        } else {
            s16x4 z = (s16x4)0;
#pragma unroll
            for (int j = 0; j < 4; ++j) *(s16x4*)&ABs[rr][4 * lane + 256 * j] = z;
        }
#pragma unroll
        for (int m = 32; m >= 1; m >>= 1) ss += __shfl_xor(ss, m, 64);
        float mag = sqrtf(ss);
        if (lane == 0) {
            magS[rr]  = tanhf(2.0f * mag);                       // 0 for invalid
            rmagS[rr] = (mag > 1e-6f) ? (1.0f / mag) : 0.0f;
        }
    }
    RAWBAR();

    // helpers needing only magS/rmagS (visible to all after next bar)
    if (tid < NR) mrS[tid] = 0.6f * magS[tid] * rmagS[tid];
    if (tid < MTO) {
        int w = edge ? ((tid < 8) ? tid : 8) : 8;
        float rw = (w > 1) ? 0.9f / (float)(w - 1) : 0.f;
        float s = 0.f;
#pragma unroll
        for (int a = 1; a <= 8; ++a) {
            float lin = (a <= w) ? ((w > 1) ? (0.1f + rw * (float)(w - a)) : 0.1f) : 0.f;
            s += lin * magS[tid + 8 - a];
        }
        rwsS[tid] = 1.0f / fmaxf(s, 1e-8f);
    }

    // ---- Phase 2: gemm1 [48 x 512], K=1024, 4-deep B ring. wave owns g [32w,32w+32) ----
    f32x4 acc1[3][2];
#pragma unroll
    for (int mt = 0; mt < 3; ++mt)
#pragma unroll
        for (int nt = 0; nt < 2; ++nt) acc1[mt][nt] = (f32x4)0.f;
    {
        const short8* Bb = Bp1 + (size_t)quad * G_ + wave * 32 + l15;
        short8 q0[2], q1[2], q2[2], q3[2];
        q0[0] = Bb[0];          q0[1] = Bb[16];
        q1[0] = Bb[4 * G_];     q1[1] = Bb[4 * G_ + 16];
        q2[0] = Bb[8 * G_];     q2[1] = Bb[8 * G_ + 16];
        q3[0] = Bb[12 * G_];    q3[1] = Bb[12 * G_ + 16];
#pragma unroll
        for (int k4 = 0; k4 < 32; k4 += 4) {
            G1Q3(k4 + 0, q0); if (k4 < 28) { q0[0] = Bb[(size_t)(k4 + 4) * 4 * G_]; q0[1] = Bb[(size_t)(k4 + 4) * 4 * G_ + 16]; }
            G1Q3(k4 + 1, q1); if (k4 < 28) { q1[0] = Bb[(size_t)(k4 + 5) * 4 * G_]; q1[1] = Bb[(size_t)(k4 + 5) * 4 * G_ + 16]; }
            G1Q3(k4 + 2, q2); if (k4 < 28) { q2[0] = Bb[(size_t)(k4 + 6) * 4 * G_]; q2[1] = Bb[(size_t)(k4 + 6) * 4 * G_ + 16]; }
            G1Q3(k4 + 3, q3); if (k4 < 28) { q3[0] = Bb[(size_t)(k4 + 7) * 4 * G_]; q3[1] = Bb[(size_t)(k4 + 7) * 4 * G_ + 16]; }
        }
    }
    RAWBAR();                    // mrS/rwsS visible

    // ---- Phase 3: normed-part 8-tap FIR over raw diffs. lane owns column d = tid ----
    float np_[MTO];
    {
        float pr[8];
#pragma unroll
        for (int r = 0; r < 8; ++r) pr[r] = mrS[r] * fbs(ABs[r][tid]);
        if (!edge) {
#pragma unroll
            for (int i = 0; i < MTO; ++i) {
                float s = 0.f;
#pragma unroll
                for (int a = 1; a <= 8; ++a)
                    s += (0.1f + (0.9f / 7.f) * (float)(8 - a)) * pr[(i + 8 - a) & 7];
                np_[i] = s;
                if (i < 31) pr[i & 7] = mrS[i + 8] * fbs(ABs[i + 8][tid]);
            }
        } else {
#pragma unroll
            for (int i = 0; i < MTO; ++i) {
                int w = (i < 8) ? i : 8;
                float rw = (w > 1) ? 0.9f / (float)(w - 1) : 0.f;
                float s = 0.f;
#pragma unroll
                for (int a = 1; a <= 8; ++a) {
                    float lin = (a <= w) ? ((w > 1) ? (0.1f + rw * (float)(w - a)) : 0.1f) : 0.f;
                    s += lin * pr[(i + 8 - a) & 7];
                }
                np_[i] = s;
                if (i < 31) pr[i & 7] = mrS[i + 8] * fbs(ABs[i + 8][tid]);
            }
        }
    }

    // ---- Phase 4: softmax (no max-sub; logits in [-2,2]); unnormalized exp ----
    float psum[3][4];
#pragma unroll
    for (int mt = 0; mt < 3; ++mt)
#pragma unroll
        for (int r2 = 0; r2 < 4; ++r2) psum[mt][r2] = 0.f;
    {
        float rmv[3][4];
#pragma unroll
        for (int mt = 0; mt < 3; ++mt)
#pragma unroll
            for (int r2 = 0; r2 < 4; ++r2) rmv[mt][r2] = rmagS[mt * 16 + quad * 4 + r2];
#pragma unroll
        for (int mt = 0; mt < 3; ++mt)
#pragma unroll
            for (int nt = 0; nt < 2; ++nt) {
                float rgv = rg2s[wave * 32 + nt * 16 + l15];
#pragma unroll
                for (int r2 = 0; r2 < 4; ++r2) {
                    float e = __expf(acc1[mt][nt][r2] * rgv * rmv[mt][r2]);
                    acc1[mt][nt][r2] = e;
                    psum[mt][r2] += e;
                }
            }
#pragma unroll
        for (int m = 8; m >= 1; m >>= 1)
#pragma unroll
            for (int mt = 0; mt < 3; ++mt)
#pragma unroll
                for (int r2 = 0; r2 < 4; ++r2)
                    psum[mt][r2] += __shfl_xor(psum[mt][r2], m, 16);
    }
    RAWBAR();                    // all FIR/gemm1 reads of ABs done -> safe to overwrite
    // W (exp) -> ABs cols 0..511; partial sums -> pred
#pragma unroll
    for (int mt = 0; mt < 3; ++mt)
#pragma unroll
        for (int nt = 0; nt < 2; ++nt)
#pragma unroll
            for (int r2 = 0; r2 < 4; ++r2)
                ABs[mt * 16 + quad * 4 + r2][wave * 32 + nt * 16 + l15] =
                    to_bf16(acc1[mt][nt][r2]);
    if (l15 == 0) {
#pragma unroll
        for (int mt = 0; mt < 3; ++mt)
#pragma unroll
            for (int r2 = 0; r2 < 4; ++r2)
                pred[mt * 16 + quad * 4 + r2][wave] = psum[mt][r2];
    }
    RAWBAR();
    if (tid < NR) {
        float s = 0.f;
#pragma unroll
        for (int w2 = 0; w2 < 16; ++w2) s += pred[tid][w2];
        cvS[tid] = 0.4f * magS[tid] / s;     // folds magw, 0.4, 1/sumexp
    }
    RAWBAR();

    // ---- Phase 5: V-build: V[i][g] = sum_a lin*cvS[i+8-a] * W[i+8-a][g]. wave: i=2w,2w+1 ----
#pragma unroll
    for (int ii = 0; ii < 2; ++ii) {
        int i = wave * 2 + ii;
        int w = edge ? ((i < 8) ? i : 8) : 8;
        float rw = (w > 1) ? 0.9f / (float)(w - 1) : 0.f;
        float c[8];
#pragma unroll
        for (int a = 1; a <= 8; ++a) {
            float lin = (a <= w) ? ((w > 1) ? (0.1f + rw * (float)(w - a)) : 0.1f) : 0.f;
            c[a - 1] = lin * cvS[i + 8 - a];
        }
        float v[8];
#pragma unroll
        for (int j = 0; j < 8; ++j) v[j] = 0.f;
#pragma unroll
        for (int a = 1; a <= 8; ++a) {
            short8 e = *(const short8*)&ABs[i + 8 - a][lane * 8];
#pragma unroll
            for (int j = 0; j < 8; ++j) v[j] += c[a - 1] * fbs(e[j]);
        }
        short8 vo;
#pragma unroll
        for (int j = 0; j < 8; ++j) vo[j] = to_bf16(v[j]);
        *(short8*)&Vs[i][lane * 8] = vo;
    }
    RAWBAR();

    // ---- Phase 6: gemm2 [32 x 1024], K=512, two 32-d halves; IP -> ABs (bf16) ----
    short* IPb = &ABs[0][0];
#pragma unroll
    for (int half = 0; half < 2; ++half) {
        f32x4 acc2[2][2];
#pragma unroll
        for (int mt = 0; mt < 2; ++mt)
#pragma unroll
            for (int nt = 0; nt < 2; ++nt) acc2[mt][nt] = (f32x4)0.f;
        const short8* Bb2 = Bp2 + (size_t)quad * D_ + wave * 64 + half * 32 + l15;
        short8 bc0 = Bb2[0], bc1 = Bb2[16], bn0, bn1;
#pragma unroll
        for (int ks = 0; ks < 16; ++ks) {
            if (ks < 15) {
                const short8* Bx = Bb2 + (size_t)(ks + 1) * 4 * D_;
                bn0 = Bx[0]; bn1 = Bx[16];
            }
            short8 a0 = *(const short8*)&Vs[l15][ks * 32 + quad * 8];
            short8 a1 = *(const short8*)&Vs[16 + l15][ks * 32 + quad * 8];
            acc2[0][0] = MF(a0, bc0, acc2[0][0]); acc2[0][1] = MF(a0, bc1, acc2[0][1]);
            acc2[1][0] = MF(a1, bc0, acc2[1][0]); acc2[1][1] = MF(a1, bc1, acc2[1][1]);
            bc0 = bn0; bc1 = bn1;
        }
#pragma unroll
        for (int mt = 0; mt < 2; ++mt)
#pragma unroll
            for (int ntl = 0; ntl < 2; ++ntl) {
                int d2 = wave * 64 + half * 32 + ntl * 16 + l15;
#pragma unroll
                for (int r2 = 0; r2 < 4; ++r2)
                    IPb[(size_t)(mt * 16 + quad * 4 + r2) * ABST2 + d2] =
                        to_bf16(acc2[mt][ntl][r2]);
            }
    }
    RAWBAR();

    // ---- Phase 7: out = (NP + IP) / wsum. lane owns column d = tid ----
    {
        float* ob = out + ((size_t)b * S_ + s0) * D_ + tid;
#pragma unroll
        for (int i = 0; i < MTO; ++i) {
            float ip = fbs(IPb[(size_t)i * ABST2 + tid]);
            ob[(size_t)i * D_] = (np_[i] + ip) * rwsS[i];
        }
    }
}

// ---------------------------------------------------------------------------
extern "C" void kernel_launch(void* const* d_in, const int* in_sizes, int n_in,
                              void* d_out, int out_size, void* d_ws, size_t ws_size,
                              hipStream_t stream) {
    const float* emb  = (const float*)d_in[0];
    const float* guid = (const float*)d_in[1];
    float* out = (float*)d_out;
    char* ws = (char*)d_ws;

    float*  rg2 = (float*)(ws + WSOFF_RG2);
    short8* Bp1 = (short8*)(ws + WSOFF_BP1);
    short8* Bp2 = (short8*)(ws + WSOFF_BP2);

    prep_kernel<<<192, 256, 0, stream>>>(guid, rg2, Bp1, Bp2);
    fused_kernel<<<256, 1024, 0, stream>>>(emb, Bp1, Bp2, rg2, out);
}